// Round 1
// baseline (620.624 us; speedup 1.0000x reference)
//
#include <hip/hip_runtime.h>
#include <math.h>

constexpr int D    = 256;   // feature dim
constexpr int H    = 128;   // hidden dim
constexpr int CHUNK = 32;   // d-chunk staged in LDS per iteration
constexpr int NPB1 = 256;   // nodes per block, pass 1
constexpr int LSTR = 33;    // padded LDS row stride (floats)
constexpr int NPB3 = 64;    // nodes per block, pass 3

__device__ __forceinline__ unsigned int enc_f(float f) {
  unsigned int b = __float_as_uint(f);
  return (b & 0x80000000u) ? ~b : (b | 0x80000000u);
}
__device__ __forceinline__ float dec_f(unsigned int u) {
  return __uint_as_float((u & 0x80000000u) ? (u ^ 0x80000000u) : ~u);
}

// ---------------- Pass 1: scores[n] = relu(x[n]@W1 + b1) @ W2 + b2 ----------
// One node per thread; h[128] accumulators in VGPRs; x staged in LDS in
// 32-wide d-chunks; W1 accessed at wave-uniform addresses (scalar loads).
extern "C" __global__ void __launch_bounds__(256)
k_scores(const float* __restrict__ x, const float* __restrict__ W1,
         const float* __restrict__ b1, const float* __restrict__ W2,
         const float* __restrict__ b2, float* __restrict__ scores,
         unsigned int* __restrict__ gmax, int N)
{
  __shared__ float ldsx[NPB1 * LSTR];   // 256 nodes x 32 d, padded: 33792 B
  __shared__ float wred[4];
  const int t = threadIdx.x;
  const int n0 = blockIdx.x * NPB1;
  const int node = n0 + t;

  float acc[H];
#pragma unroll
  for (int j = 0; j < H; ++j) acc[j] = b1[j];

  for (int c = 0; c < D / CHUNK; ++c) {
    const int d0 = c * CHUNK;
    __syncthreads();   // protect ldsx from previous chunk's readers
    // stage x[n0..n0+255][d0..d0+31]: 8 threads per row, float4 each
#pragma unroll
    for (int k = 0; k < 8; ++k) {
      const int r = (t >> 3) + k * 32;
      const int nn = n0 + r;
      if (nn < N) {
        const float4 v =
            *reinterpret_cast<const float4*>(x + (size_t)nn * D + d0 + (t & 7) * 4);
        float* p = &ldsx[r * LSTR + (t & 7) * 4];
        p[0] = v.x; p[1] = v.y; p[2] = v.z; p[3] = v.w;
      }
    }
    __syncthreads();
#pragma unroll 1
    for (int dd = 0; dd < CHUNK; ++dd) {
      const float xv = ldsx[t * LSTR + dd];               // conflict-free (stride 33)
      const float* wrow = W1 + (size_t)(d0 + dd) * H;     // wave-uniform -> s_load
#pragma unroll
      for (int j = 0; j < H; ++j) acc[j] = fmaf(xv, wrow[j], acc[j]);
    }
  }

  float s = b2[0];
#pragma unroll
  for (int j = 0; j < H; ++j) s = fmaf(fmaxf(acc[j], 0.0f), W2[j], s);

  if (node < N) scores[node] = s;
  float m = (node < N) ? s : -INFINITY;
#pragma unroll
  for (int off = 32; off > 0; off >>= 1) m = fmaxf(m, __shfl_down(m, off, 64));
  if ((t & 63) == 0) wred[t >> 6] = m;
  __syncthreads();
  if (t == 0) {
    m = fmaxf(fmaxf(wred[0], wred[1]), fmaxf(wred[2], wred[3]));
    atomicMax(gmax, enc_f(m));
  }
}

// ---------------- Pass 2: Z = sum(exp(s - max)) -----------------------------
extern "C" __global__ void __launch_bounds__(256)
k_expsum(const float* __restrict__ scores, const unsigned int* __restrict__ gmax,
         float* __restrict__ zacc, int N)
{
  const float m = dec_f(*gmax);
  float sum = 0.0f;
  for (int i = blockIdx.x * blockDim.x + threadIdx.x; i < N;
       i += gridDim.x * blockDim.x)
    sum += __expf(scores[i] - m);
#pragma unroll
  for (int off = 32; off > 0; off >>= 1) sum += __shfl_down(sum, off, 64);
  __shared__ float wred[4];
  if ((threadIdx.x & 63) == 0) wred[threadIdx.x >> 6] = sum;
  __syncthreads();
  if (threadIdx.x == 0)
    atomicAdd(zacc, wred[0] + wred[1] + wred[2] + wred[3]);
}

// ---------------- Pass 3: pooled[b] += x[n] * w[n] (batch sorted) -----------
// 64 threads = 1 wave; each thread owns 4 columns (float4). Register
// accumulate within a segment run, atomic flush at boundaries.
extern "C" __global__ void __launch_bounds__(64)
k_pool(const float* __restrict__ x, const int* __restrict__ batch,
       const float* __restrict__ scores, const unsigned int* __restrict__ gmax,
       const float* __restrict__ zacc, float* __restrict__ out, int N)
{
  const int t = threadIdx.x;
  const int n0 = blockIdx.x * NPB3;
  const int n1 = min(n0 + NPB3, N);
  if (n0 >= n1) return;
  const float m = dec_f(*gmax);
  const float invZ = 1.0f / (*zacc);

  float4 acc = make_float4(0.f, 0.f, 0.f, 0.f);
  int bprev = batch[n0];
  for (int n = n0; n < n1; ++n) {
    const int b = batch[n];
    if (b != bprev) {
      float* o = out + (size_t)bprev * D + t * 4;
      atomicAdd(o + 0, acc.x); atomicAdd(o + 1, acc.y);
      atomicAdd(o + 2, acc.z); atomicAdd(o + 3, acc.w);
      acc = make_float4(0.f, 0.f, 0.f, 0.f);
      bprev = b;
    }
    const float w = __expf(scores[n] - m) * invZ;
    const float4 xv = *reinterpret_cast<const float4*>(x + (size_t)n * D + t * 4);
    acc.x = fmaf(xv.x, w, acc.x);
    acc.y = fmaf(xv.y, w, acc.y);
    acc.z = fmaf(xv.z, w, acc.z);
    acc.w = fmaf(xv.w, w, acc.w);
  }
  float* o = out + (size_t)bprev * D + t * 4;
  atomicAdd(o + 0, acc.x); atomicAdd(o + 1, acc.y);
  atomicAdd(o + 2, acc.z); atomicAdd(o + 3, acc.w);
}

extern "C" void kernel_launch(void* const* d_in, const int* in_sizes, int n_in,
                              void* d_out, int out_size, void* d_ws, size_t ws_size,
                              hipStream_t stream)
{
  const float* x     = (const float*)d_in[0];
  const int*   batch = (const int*)d_in[1];
  // d_in[2] = num_segments (unused; B = out_size / D)
  const float* W1 = (const float*)d_in[3];
  const float* b1 = (const float*)d_in[4];
  const float* W2 = (const float*)d_in[5];
  const float* b2 = (const float*)d_in[6];
  const int N = in_sizes[1];

  unsigned int* gmax = (unsigned int*)d_ws;                 // [0]: encoded max
  float* zacc        = (float*)((char*)d_ws + 64);          // Z accumulator
  float* scores      = (float*)((char*)d_ws + 256);         // N floats

  hipMemsetAsync(d_out, 0, (size_t)out_size * sizeof(float), stream);
  hipMemsetAsync(d_ws, 0, 256, stream);

  const int g1 = (N + NPB1 - 1) / NPB1;
  k_scores<<<g1, 256, 0, stream>>>(x, W1, b1, W2, b2, scores, gmax, N);

  int g2 = (N + 255) / 256; if (g2 > 2048) g2 = 2048;
  k_expsum<<<g2, 256, 0, stream>>>(scores, gmax, zacc, N);

  const int g3 = (N + NPB3 - 1) / NPB3;
  k_pool<<<g3, 64, 0, stream>>>(x, batch, scores, gmax, zacc, (float*)d_out, N);
}

// Round 2
// 238.754 us; speedup vs baseline: 2.5994x; 2.5994x over previous
//
#include <hip/hip_runtime.h>
#include <math.h>

typedef __attribute__((ext_vector_type(8))) short bf16x8;
typedef __attribute__((ext_vector_type(4))) float f32x4;

constexpr int D = 256;       // feature dim (K of GEMM)
constexpr int H = 128;       // hidden dim
constexpr int KSTEPS = D / 32;   // 8 MFMA k-steps
constexpr int HTILES = H / 16;   // 8 n-tiles
constexpr int NPB3 = 64;         // nodes per block, pass 3

__device__ __forceinline__ unsigned int enc_f(float f) {
  unsigned int b = __float_as_uint(f);
  return (b & 0x80000000u) ? ~b : (b | 0x80000000u);
}
__device__ __forceinline__ float dec_f(unsigned int u) {
  return __uint_as_float((u & 0x80000000u) ? (u ^ 0x80000000u) : ~u);
}
// exact split: hi = bf16-truncate(x) (x - hi is exact), lo = bf16-trunc(x - hi)
__device__ __forceinline__ float trunc_bf(float a) {
  return __uint_as_float(__float_as_uint(a) & 0xFFFF0000u);
}
__device__ __forceinline__ unsigned int pack2_bf(float a, float b) {
  return (__float_as_uint(a) >> 16) | (__float_as_uint(b) & 0xFFFF0000u);
}

union FragU { uint4 u; bf16x8 f; };

// ---- Pre-pack W1 into per-lane MFMA B-fragment order (hi/lo bf16) ----------
// Index g = (kstep*8 + htile)*64 + lane; element j: K = kstep*32+(lane>>4)*8+j,
// N(col) = htile*16 + (lane&15).
extern "C" __global__ void __launch_bounds__(256)
k_pack(const float* __restrict__ W1, uint4* __restrict__ phi,
       uint4* __restrict__ plo)
{
  const int g = blockIdx.x * 256 + threadIdx.x;       // 0..4095
  const int c = g >> 9, ht = (g >> 6) & 7, l = g & 63;
  const int kbase = c * 32 + (l >> 4) * 8;
  const int col = ht * 16 + (l & 15);
  float v[8], lo[8];
#pragma unroll
  for (int i = 0; i < 8; ++i) {
    v[i] = W1[(size_t)(kbase + i) * H + col];
    lo[i] = v[i] - trunc_bf(v[i]);
  }
  uint4 h4, l4;
  h4.x = pack2_bf(v[0], v[1]); h4.y = pack2_bf(v[2], v[3]);
  h4.z = pack2_bf(v[4], v[5]); h4.w = pack2_bf(v[6], v[7]);
  l4.x = pack2_bf(lo[0], lo[1]); l4.y = pack2_bf(lo[2], lo[3]);
  l4.z = pack2_bf(lo[4], lo[5]); l4.w = pack2_bf(lo[6], lo[7]);
  phi[g] = h4; plo[g] = l4;
}

// ---- Pass 1: scores via MFMA (x@W1 with hi/lo split), relu, @W2 ------------
// 256 threads = 4 waves; each wave owns 64 nodes (4 stripes of 16).
extern "C" __global__ void __launch_bounds__(256, 2)
k_scores_mfma(const float* __restrict__ x, const uint4* __restrict__ phi,
              const uint4* __restrict__ plo, const float* __restrict__ b1,
              const float* __restrict__ W2, const float* __restrict__ b2,
              float* __restrict__ scores, unsigned int* __restrict__ gmax, int N)
{
  const int t = threadIdx.x;
  const int l = t & 63;
  const int w = t >> 6;
  const int wbase = blockIdx.x * 256 + w * 64;
  const int lg = l >> 4;      // k-group (0..3)
  const int lr = l & 15;      // M-row (A) / N-col (B,C)

  f32x4 acc[4][HTILES] = {};
  bool sv[4];
#pragma unroll
  for (int s = 0; s < 4; ++s) sv[s] = (wbase + s * 16) < N;  // N%16==0

#pragma unroll 1
  for (int c = 0; c < KSTEPS; ++c) {
    FragU ahi[4], alo[4];
#pragma unroll
    for (int s = 0; s < 4; ++s) {
      float v[8];
      if (sv[s]) {
        const float* p = x + (size_t)(wbase + s * 16 + lr) * D + c * 32 + lg * 8;
        const float4 u0 = *reinterpret_cast<const float4*>(p);
        const float4 u1 = *reinterpret_cast<const float4*>(p + 4);
        v[0] = u0.x; v[1] = u0.y; v[2] = u0.z; v[3] = u0.w;
        v[4] = u1.x; v[5] = u1.y; v[6] = u1.z; v[7] = u1.w;
      } else {
#pragma unroll
        for (int i = 0; i < 8; ++i) v[i] = 0.0f;
      }
      float lo[8];
#pragma unroll
      for (int i = 0; i < 8; ++i) lo[i] = v[i] - trunc_bf(v[i]);
      ahi[s].u.x = pack2_bf(v[0], v[1]);  ahi[s].u.y = pack2_bf(v[2], v[3]);
      ahi[s].u.z = pack2_bf(v[4], v[5]);  ahi[s].u.w = pack2_bf(v[6], v[7]);
      alo[s].u.x = pack2_bf(lo[0], lo[1]); alo[s].u.y = pack2_bf(lo[2], lo[3]);
      alo[s].u.z = pack2_bf(lo[4], lo[5]); alo[s].u.w = pack2_bf(lo[6], lo[7]);
    }
#pragma unroll
    for (int ht = 0; ht < HTILES; ++ht) {
      FragU bhi, blo;
      bhi.u = phi[(c * 8 + ht) * 64 + l];
      blo.u = plo[(c * 8 + ht) * 64 + l];
#pragma unroll
      for (int s = 0; s < 4; ++s) {
        acc[s][ht] = __builtin_amdgcn_mfma_f32_16x16x32_bf16(ahi[s].f, bhi.f, acc[s][ht], 0, 0, 0);
        acc[s][ht] = __builtin_amdgcn_mfma_f32_16x16x32_bf16(ahi[s].f, blo.f, acc[s][ht], 0, 0, 0);
        acc[s][ht] = __builtin_amdgcn_mfma_f32_16x16x32_bf16(alo[s].f, bhi.f, acc[s][ht], 0, 0, 0);
      }
    }
  }

  // epilogue: score = relu(h + b1) @ W2 + b2 ; h[row][col] in acc
  float bv[HTILES], wv[HTILES];
#pragma unroll
  for (int ht = 0; ht < HTILES; ++ht) {
    bv[ht] = b1[ht * 16 + lr];
    wv[ht] = W2[ht * 16 + lr];
  }
  const float bias2 = b2[0];
  float mymax = -INFINITY;
#pragma unroll
  for (int s = 0; s < 4; ++s) {
    float sc[4];
#pragma unroll
    for (int r = 0; r < 4; ++r) {
      float p = 0.0f;
#pragma unroll
      for (int ht = 0; ht < HTILES; ++ht)
        p = fmaf(fmaxf(acc[s][ht][r] + bv[ht], 0.0f), wv[ht], p);
#pragma unroll
      for (int off = 1; off < 16; off <<= 1) p += __shfl_xor(p, off, 64);
      sc[r] = p + bias2;
    }
    if (sv[s] && lr == 0) {
      *reinterpret_cast<float4*>(scores + wbase + s * 16 + lg * 4) =
          make_float4(sc[0], sc[1], sc[2], sc[3]);
      mymax = fmaxf(fmaxf(fmaxf(sc[0], sc[1]), fmaxf(sc[2], sc[3])), mymax);
    }
  }
#pragma unroll
  for (int off = 16; off < 64; off <<= 1)
    mymax = fmaxf(mymax, __shfl_xor(mymax, off, 64));
  if (l == 0) atomicMax(gmax, enc_f(mymax));
}

// ---- Pass 2: Z = sum(exp(s - max)) -----------------------------------------
extern "C" __global__ void __launch_bounds__(256)
k_expsum(const float* __restrict__ scores, const unsigned int* __restrict__ gmax,
         float* __restrict__ zacc, int N)
{
  const float m = dec_f(*gmax);
  float sum = 0.0f;
  for (int i = blockIdx.x * blockDim.x + threadIdx.x; i < N;
       i += gridDim.x * blockDim.x)
    sum += __expf(scores[i] - m);
#pragma unroll
  for (int off = 32; off > 0; off >>= 1) sum += __shfl_down(sum, off, 64);
  __shared__ float wred[4];
  if ((threadIdx.x & 63) == 0) wred[threadIdx.x >> 6] = sum;
  __syncthreads();
  if (threadIdx.x == 0)
    atomicAdd(zacc, wred[0] + wred[1] + wred[2] + wred[3]);
}

// ---- Pass 3: pooled[b] += x[n] * w[n] (batch sorted) -----------------------
extern "C" __global__ void __launch_bounds__(64)
k_pool(const float* __restrict__ x, const int* __restrict__ batch,
       const float* __restrict__ scores, const unsigned int* __restrict__ gmax,
       const float* __restrict__ zacc, float* __restrict__ out, int N)
{
  const int t = threadIdx.x;
  const int n0 = blockIdx.x * NPB3;
  const int n1 = min(n0 + NPB3, N);
  if (n0 >= n1) return;
  const float m = dec_f(*gmax);
  const float invZ = 1.0f / (*zacc);

  float4 acc = make_float4(0.f, 0.f, 0.f, 0.f);
  int bprev = batch[n0];
  for (int n = n0; n < n1; ++n) {
    const int b = batch[n];
    if (b != bprev) {
      float* o = out + (size_t)bprev * D + t * 4;
      atomicAdd(o + 0, acc.x); atomicAdd(o + 1, acc.y);
      atomicAdd(o + 2, acc.z); atomicAdd(o + 3, acc.w);
      acc = make_float4(0.f, 0.f, 0.f, 0.f);
      bprev = b;
    }
    const float wgt = __expf(scores[n] - m) * invZ;
    const float4 xv = *reinterpret_cast<const float4*>(x + (size_t)n * D + t * 4);
    acc.x = fmaf(xv.x, wgt, acc.x);
    acc.y = fmaf(xv.y, wgt, acc.y);
    acc.z = fmaf(xv.z, wgt, acc.z);
    acc.w = fmaf(xv.w, wgt, acc.w);
  }
  float* o = out + (size_t)bprev * D + t * 4;
  atomicAdd(o + 0, acc.x); atomicAdd(o + 1, acc.y);
  atomicAdd(o + 2, acc.z); atomicAdd(o + 3, acc.w);
}

extern "C" void kernel_launch(void* const* d_in, const int* in_sizes, int n_in,
                              void* d_out, int out_size, void* d_ws, size_t ws_size,
                              hipStream_t stream)
{
  const float* x     = (const float*)d_in[0];
  const int*   batch = (const int*)d_in[1];
  const float* W1 = (const float*)d_in[3];
  const float* b1 = (const float*)d_in[4];
  const float* W2 = (const float*)d_in[5];
  const float* b2 = (const float*)d_in[6];
  const int N = in_sizes[1];

  unsigned int* gmax = (unsigned int*)d_ws;                    // encoded max
  float* zacc        = (float*)((char*)d_ws + 64);             // Z accumulator
  uint4* phi         = (uint4*)((char*)d_ws + 256);            // 64 KB
  uint4* plo         = (uint4*)((char*)d_ws + 256 + 65536);    // 64 KB
  float* scores      = (float*)((char*)d_ws + 256 + 131072);   // N floats

  hipMemsetAsync(d_out, 0, (size_t)out_size * sizeof(float), stream);
  hipMemsetAsync(d_ws, 0, 256, stream);

  k_pack<<<16, 256, 0, stream>>>(W1, phi, plo);

  const int g1 = (N + 255) / 256;
  k_scores_mfma<<<g1, 256, 0, stream>>>(x, phi, plo, b1, W2, b2, scores, gmax, N);

  int g2 = (N + 255) / 256; if (g2 > 2048) g2 = 2048;
  k_expsum<<<g2, 256, 0, stream>>>(scores, gmax, zacc, N);

  const int g3 = (N + NPB3 - 1) / NPB3;
  k_pool<<<g3, 64, 0, stream>>>(x, batch, scores, gmax, zacc, (float*)d_out, N);
}